// Round 2
// baseline (528.322 us; speedup 1.0000x reference)
//
#include <hip/hip_runtime.h>
#include <hip/hip_bf16.h>
#include <stdint.h>

// Problem constants: B=8, S=4096, H=1024, E=8 -> N = 32768 tokens.
#define HDIM 1024
#define NEXP 8
#define NTOK 32768
#define BM 128
#define BN 128
#define BK 32

typedef __attribute__((ext_vector_type(4))) float f32x4;
typedef __attribute__((ext_vector_type(8))) short bf16x8;

// fp32 -> bf16 bits, round-to-nearest-even (transpose kernel)
__device__ __forceinline__ unsigned short f2bf(float f) {
  union { float f; unsigned u; } v; v.f = f;
  unsigned r = v.u + 0x7FFF + ((v.u >> 16) & 1);
  return (unsigned short)(r >> 16);
}

// fp32 -> bf16 bits via HIP cast (RNE; compiler lowers to v_cvt_pk pairs, m240)
__device__ __forceinline__ unsigned short bfbits(float f) {
  union { __hip_bfloat16 b; unsigned short u; } cv;
  cv.b = __float2bfloat16(f);
  return cv.u;
}

// async global->LDS, 16B per lane. LDS dest must be wave-uniform base + lane*16.
__device__ __forceinline__ void gload_lds16(const void* g, void* l) {
  __builtin_amdgcn_global_load_lds(
      (__attribute__((address_space(1))) void*)(g),
      (__attribute__((address_space(3))) void*)(l), 16, 0, 0);
}

// ---------------------------------------------------------------------------
// Kernel 1: We [k][n] fp32 -> Wt [n][k] bf16 (transpose + convert). Unchanged.
// ---------------------------------------------------------------------------
__global__ __launch_bounds__(256) void transpose_convert(
    const float* __restrict__ We, unsigned short* __restrict__ wt) {
  __shared__ float tile[64][65];
  const int bj = blockIdx.x, bi = blockIdx.y;
  const int tx = threadIdx.x & 63, ty = threadIdx.x >> 6;
#pragma unroll
  for (int i = 0; i < 16; ++i) {
    int row = i * 4 + ty;
    tile[row][tx] = We[(size_t)(bi * 64 + row) * HDIM + bj * 64 + tx];
  }
  __syncthreads();
#pragma unroll
  for (int i = 0; i < 16; ++i) {
    int row = i * 4 + ty;
    wt[(size_t)(bj * 64 + row) * HDIM + bi * 64 + tx] = f2bf(tile[tx][row]);
  }
}

// ---------------------------------------------------------------------------
// Kernel 2 (FUSED): router + fp32->bf16 convert + GEMM + scaled epilogue.
//   C[m][n] = (x[m][:] @ We[:][n] + be[n]) * p[m],  p = softmax-max-prob.
// Structure = proven m97-style 128x128/BK32/4-wave MFMA kernel, changed:
//  - A staged as FP32 via global_load_lds (no xb intermediate at all).
//    Source mapping: chunk c (0..1023): gq=c>>7, row=c&127 holds
//    x[m0+row][k0+gq*4..+4]. Frag read granule = 2q*128+row -> bank-group
//    col&7 (even, conflict-free); router column read -> lane&7 (even).
//  - frags converted fp32->bf16 in-register (RNE, identical bits to old xb).
//  - B source remapped: chunk c: q=c>>7, row=c&127 -> frag granule
//    q*128+(n-row): bank-group col&7 (fixes the 8.4M conflicts of row*4+q).
//  - router: wave w accumulates logits for tokens (w&1)*64+lane over
//    k-slice (w>>1)*16..+16 per K-step (wave-uniform Wg -> s_load);
//    2-way LDS reduce + softmax -> pb[128] applied in epilogue.
// Router math stays fp32 (exact x values; only summation order differs).
// ---------------------------------------------------------------------------
__global__ __launch_bounds__(256) void moe_fused(
    const float* __restrict__ x, const float* __restrict__ Wg,
    const float* __restrict__ bg, const unsigned short* __restrict__ Bt,
    const float* __restrict__ be, float* __restrict__ out) {
  __shared__ __align__(16) float As[BM * BK];           // 16 KB fp32, granule map
  __shared__ __align__(16) unsigned short Bs[BN * BK];  // 8 KB bf16, granule map
  __shared__ float part[2][BM][NEXP];                   // 8 KB router partials
  __shared__ float pb[BM];

  const int t = threadIdx.x;
  const int lane = t & 63;
  const int wu = __builtin_amdgcn_readfirstlane(t >> 6);  // wave id, SGPR

  const unsigned lin = blockIdx.x;                   // 2048 blocks
  const unsigned xcd = lin & 7, idx = lin >> 3;      // XCD-aware swizzle
  const int n0 = (int)(idx & 7) * BN;                // 8 n-blocks inner
  const int m0 = (int)(xcd * 32 + (idx >> 3)) * BM;  // 32 m-panels per XCD

  // A staging: 4 chunks/thread. chunk c: gq=c>>7, row=c&127; LDS off = c*16B.
  const float* ga[4];
  float* la[4];
#pragma unroll
  for (int i = 0; i < 4; ++i) {
    const int c = t + 256 * i;
    ga[i] = x + (size_t)(m0 + (c & 127)) * HDIM + (c >> 7) * 4;
    la[i] = As + (size_t)c * 4;
  }
  // B staging: 2 chunks/thread. chunk c: q=c>>7, row=c&127.
  const unsigned short* gb[2];
  unsigned short* lb[2];
#pragma unroll
  for (int i = 0; i < 2; ++i) {
    const int c = t + 256 * i;
    gb[i] = Bt + (size_t)(n0 + (c & 127)) * HDIM + (c >> 7) * 8;
    lb[i] = Bs + (size_t)c * 8;
  }

  const int wm = (wu >> 1) * 64, wn = (wu & 1) * 64;
  const int col = lane & 15, q = lane >> 4;  // frag: row=col, k=q*8+s
  const int tr = (wu & 1) * 64 + lane;       // router token row
  const int kqr = (wu >> 1) * 4;             // router granule base (gq units)

  f32x4 acc[4][4] = {};
  float racc[NEXP] = {};

  for (int k0 = 0; k0 < HDIM; k0 += BK) {
#pragma unroll
    for (int i = 0; i < 4; ++i) gload_lds16(ga[i], la[i]);
#pragma unroll
    for (int i = 0; i < 2; ++i) gload_lds16(gb[i], lb[i]);
#pragma unroll
    for (int i = 0; i < 4; ++i) ga[i] += BK;
#pragma unroll
    for (int i = 0; i < 2; ++i) gb[i] += BK;
    __syncthreads();

    // ---- router partials: 16 fp32 per thread from LDS, Wg via s_load ----
    const float* wrow = Wg + ((size_t)k0 + (wu >> 1) * 16) * NEXP;
#pragma unroll
    for (int i = 0; i < 4; ++i) {
      const f32x4 xv = *(const f32x4*)(As + ((kqr + i) * 128 + tr) * 4);
#pragma unroll
      for (int j = 0; j < 4; ++j)
#pragma unroll
        for (int e = 0; e < NEXP; ++e)
          racc[e] += xv[j] * wrow[(i * 4 + j) * NEXP + e];
    }

    // ---- MFMA frags: A fp32->bf16 in-register, B direct ----
    bf16x8 a[4], b[4];
#pragma unroll
    for (int i = 0; i < 4; ++i) {
      const float* g0 = As + ((q * 2) * 128 + wm + i * 16 + col) * 4;
      const f32x4 lo = *(const f32x4*)g0;
      const f32x4 hi = *(const f32x4*)(g0 + 512);  // +1 granule plane (gq+1)
      union { bf16x8 v; unsigned short us[8]; } cv;
#pragma unroll
      for (int j2 = 0; j2 < 4; ++j2) {
        cv.us[j2] = bfbits(lo[j2]);
        cv.us[4 + j2] = bfbits(hi[j2]);
      }
      a[i] = cv.v;
      b[i] = *(const bf16x8*)(Bs + ((size_t)q * 128 + wn + i * 16 + col) * 8);
    }
#pragma unroll
    for (int i = 0; i < 4; ++i)
#pragma unroll
      for (int j = 0; j < 4; ++j)
        acc[i][j] =
            __builtin_amdgcn_mfma_f32_16x16x32_bf16(a[i], b[j], acc[i][j], 0, 0, 0);
    __syncthreads();
  }

  // ---- router finalize: reduce k-halves, softmax max-prob ----
#pragma unroll
  for (int e = 0; e < NEXP; ++e) part[wu >> 1][tr][e] = racc[e];
  __syncthreads();
  if (t < BM) {
    float l[NEXP];
#pragma unroll
    for (int e = 0; e < NEXP; ++e) l[e] = bg[e] + part[0][t][e] + part[1][t][e];
    float mx = l[0];
#pragma unroll
    for (int e = 1; e < NEXP; ++e) mx = fmaxf(mx, l[e]);
    float s = 0.f;
#pragma unroll
    for (int e = 0; e < NEXP; ++e) s += __expf(l[e] - mx);
    pb[t] = 1.0f / s;  // prob of argmax = exp(0)/sum
  }
  __syncthreads();

  // ---- epilogue: C/D layout col=lane&15 (n), row=q*4+r (m)  [m89/m91] ----
  float pv[4][4];
#pragma unroll
  for (int i = 0; i < 4; ++i)
#pragma unroll
    for (int r = 0; r < 4; ++r) pv[i][r] = pb[wm + i * 16 + q * 4 + r];
#pragma unroll
  for (int j = 0; j < 4; ++j) {
    const int n = n0 + wn + j * 16 + col;
    const float bev = be[n];
#pragma unroll
    for (int i = 0; i < 4; ++i) {
#pragma unroll
      for (int r = 0; r < 4; ++r) {
        const int m = m0 + wm + i * 16 + q * 4 + r;
        out[(size_t)m * HDIM + n] = (acc[i][j][r] + bev) * pv[i][r];
      }
    }
  }
}

// ---------------------------------------------------------------------------
extern "C" void kernel_launch(void* const* d_in, const int* in_sizes, int n_in,
                              void* d_out, int out_size, void* d_ws, size_t ws_size,
                              hipStream_t stream) {
  const float* x  = (const float*)d_in[0];
  const float* Wg = (const float*)d_in[1];
  const float* bg = (const float*)d_in[2];
  const float* We = (const float*)d_in[3];
  const float* be = (const float*)d_in[4];
  float* out = (float*)d_out;

  // workspace: only Wt (2,097,152 B) — xb and p eliminated by fusion.
  unsigned short* wt = (unsigned short*)d_ws;

  transpose_convert<<<dim3(16, 16), 256, 0, stream>>>(We, wt);
  moe_fused<<<2048, 256, 0, stream>>>(x, Wg, bg, wt, be, out);
}

// Round 3
// 414.674 us; speedup vs baseline: 1.2741x; 1.2741x over previous
//
#include <hip/hip_runtime.h>
#include <stdint.h>

// Problem constants: B=8, S=4096, H=1024, E=8 -> N = 32768 tokens.
#define HDIM 1024
#define NEXP 8
#define NTOK 32768
#define BM 128
#define BN 128
#define BK 64

typedef __attribute__((ext_vector_type(4))) float f32x4;
typedef __attribute__((ext_vector_type(8))) short bf16x8;

// fp32 -> bf16 bits, round-to-nearest-even
__device__ __forceinline__ unsigned short f2bf(float f) {
  union { float f; unsigned u; } v; v.f = f;
  unsigned r = v.u + 0x7FFF + ((v.u >> 16) & 1);
  return (unsigned short)(r >> 16);
}

// async global->LDS, 16B per lane. LDS dest must be wave-uniform base + lane*16.
__device__ __forceinline__ void gload_lds16(const void* g, void* l) {
  __builtin_amdgcn_global_load_lds(
      (__attribute__((address_space(1))) void*)(g),
      (__attribute__((address_space(3))) void*)(l), 16, 0, 0);
}

// ---------------------------------------------------------------------------
// Kernel 1: router (fp32 exact) + x -> bf16 conversion, one streaming pass.
// R3: no LDS, no __syncthreads. Block = 64 tokens, 512 threads.
// Thread t owns rows {16*i + (t>>5)} (i=0..3) and float columns
// 4*(t&31)..+4 of each 128-float chunk -> fully coalesced float4 reads of x
// and uint2 writes of xb. Partial logits accumulate in registers; the 32
// threads sharing a row are one half-wave -> __shfl_xor tree reduce.
// Wg is 32 KB -> L1/L2-resident vector loads. Router math stays fp32.
// ---------------------------------------------------------------------------
__global__ __launch_bounds__(512) void router_convert(
    const float* __restrict__ x, const float* __restrict__ Wg,
    const float* __restrict__ bg, unsigned short* __restrict__ xb,
    float* __restrict__ p) {
  const int t = threadIdx.x;
  const int tok0 = blockIdx.x * 64;
  const int rbase = t >> 5;  // 0..15
  const int c4 = t & 31;     // float4 column within the 128-float chunk

  float acc[4][NEXP] = {};   // partial logits for the 4 owned rows

  for (int ck = 0; ck < 8; ++ck) {
    // Wg rows used by this thread this chunk: ck*128 + c4*4 + j, j=0..3.
    const float* wbase = Wg + ((size_t)ck * 128 + c4 * 4) * NEXP;
#pragma unroll
    for (int i = 0; i < 4; ++i) {
      const int r = i * 16 + rbase;
      const size_t goff = (size_t)(tok0 + r) * HDIM + ck * 128 + c4 * 4;
      const float4 v = *(const float4*)(x + goff);
      union { unsigned short us[4]; uint2 u2; } pk;
      pk.us[0] = f2bf(v.x); pk.us[1] = f2bf(v.y);
      pk.us[2] = f2bf(v.z); pk.us[3] = f2bf(v.w);
      *(uint2*)(xb + goff) = pk.u2;
      const float fv[4] = {v.x, v.y, v.z, v.w};
#pragma unroll
      for (int j = 0; j < 4; ++j)
#pragma unroll
        for (int e = 0; e < NEXP; ++e)
          acc[i][e] += fv[j] * wbase[j * NEXP + e];
    }
  }

  // half-wave (32-lane) tree reduce: lanes sharing a row differ only in c4.
#pragma unroll
  for (int i = 0; i < 4; ++i)
#pragma unroll
    for (int e = 0; e < NEXP; ++e) {
      float v = acc[i][e];
#pragma unroll
      for (int m = 16; m >= 1; m >>= 1) v += __shfl_xor(v, m);
      acc[i][e] = v;
    }

  if (c4 == 0) {
#pragma unroll
    for (int i = 0; i < 4; ++i) {
      float l[NEXP];
#pragma unroll
      for (int e = 0; e < NEXP; ++e) l[e] = acc[i][e] + bg[e];
      float mx = l[0];
#pragma unroll
      for (int e = 1; e < NEXP; ++e) mx = fmaxf(mx, l[e]);
      float s = 0.f;
#pragma unroll
      for (int e = 0; e < NEXP; ++e) s += __expf(l[e] - mx);
      p[tok0 + i * 16 + rbase] = 1.0f / s;  // prob of argmax = exp(0)/sum
    }
  }
}

// ---------------------------------------------------------------------------
// Kernel 2: We [k][n] fp32 -> Wt [n][k] bf16 (transpose + convert). Unchanged.
// ---------------------------------------------------------------------------
__global__ __launch_bounds__(256) void transpose_convert(
    const float* __restrict__ We, unsigned short* __restrict__ wt) {
  __shared__ float tile[64][65];
  const int bj = blockIdx.x, bi = blockIdx.y;
  const int tx = threadIdx.x & 63, ty = threadIdx.x >> 6;
#pragma unroll
  for (int i = 0; i < 16; ++i) {
    int row = i * 4 + ty;
    tile[row][tx] = We[(size_t)(bi * 64 + row) * HDIM + bj * 64 + tx];
  }
  __syncthreads();
#pragma unroll
  for (int i = 0; i < 16; ++i) {
    int row = i * 4 + ty;
    wt[(size_t)(bj * 64 + row) * HDIM + bi * 64 + tx] = f2bf(tile[tx][row]);
  }
}

// ---------------------------------------------------------------------------
// Kernel 3: C[m][n] = (A[m][:] @ We[:][n] + be[n]) * p[m], bf16 MFMA.
// R3 changes vs round 1:
//  - BK=64: 16 K-iterations (half the barrier drains), 32 MFMA + 16
//    ds_read_b128 per wave per iteration. LDS 32 KB.
//  - granule-remapped LDS (verified in round 2): LDS granule g (16B) holds
//    A[m0 + (g&127)][k0 + (g>>7)*8 .. +8] (same for B rows n). Frag read
//    bank-quad = col&7 -> lane groups 0-7/8-15/... hit all 8 quads evenly
//    (round-1 layout hit 2 of 8 -> 8.4M SQ_LDS_BANK_CONFLICT).
//    gload_lds dest stays linear in lane (m104 constraint); the remap lives
//    entirely in the per-lane *source* address.
// XCD-aware swizzle unchanged: block -> XCD lin&7; n-blocks inner.
// ---------------------------------------------------------------------------
__global__ __launch_bounds__(256) void moe_gemm(
    const unsigned short* __restrict__ A, const unsigned short* __restrict__ Bt,
    const float* __restrict__ be, const float* __restrict__ p,
    float* __restrict__ out) {
  __shared__ __align__(16) unsigned short As[BM * BK];  // 16 KB, granule map
  __shared__ __align__(16) unsigned short Bs[BN * BK];  // 16 KB, granule map
  const int t = threadIdx.x;

  const unsigned lin = blockIdx.x;            // 2048 blocks
  const unsigned xcd = lin & 7, idx = lin >> 3;
  const int n0 = (int)(idx & 7) * BN;          // 8 n-blocks inner
  const int m0 = (int)(xcd * 32 + (idx >> 3)) * BM;  // 32 m-panels per XCD

  // staging: 1024 granules per tile; thread t takes chunks t + 256*i.
  // chunk c: kq = c>>7 (0..7), row = c&127.
  const unsigned short* ga[4];
  const unsigned short* gb[4];
  unsigned short* la[4];
  unsigned short* lb[4];
#pragma unroll
  for (int i = 0; i < 4; ++i) {
    const int c = t + 256 * i;
    const int row = c & 127, kq = c >> 7;
    ga[i] = A + (size_t)(m0 + row) * HDIM + kq * 8;
    gb[i] = Bt + (size_t)(n0 + row) * HDIM + kq * 8;
    la[i] = As + (size_t)c * 8;
    lb[i] = Bs + (size_t)c * 8;
  }

  const int lane = t & 63, wid = t >> 6;
  const int wm = (wid >> 1) * 64, wn = (wid & 1) * 64;
  const int col = lane & 15, q = lane >> 4;  // frag: row=col, k=q*8+s

  f32x4 acc[4][4] = {};

  for (int k0 = 0; k0 < HDIM; k0 += BK) {
#pragma unroll
    for (int i = 0; i < 4; ++i) gload_lds16(ga[i], la[i]);
#pragma unroll
    for (int i = 0; i < 4; ++i) gload_lds16(gb[i], lb[i]);
#pragma unroll
    for (int i = 0; i < 4; ++i) { ga[i] += BK; gb[i] += BK; }
    __syncthreads();
#pragma unroll
    for (int kk = 0; kk < 2; ++kk) {
      bf16x8 a[4], b[4];
#pragma unroll
      for (int i = 0; i < 4; ++i) {
        a[i] = *(const bf16x8*)(As +
                ((size_t)(kk * 4 + q) * 128 + wm + i * 16 + col) * 8);
        b[i] = *(const bf16x8*)(Bs +
                ((size_t)(kk * 4 + q) * 128 + wn + i * 16 + col) * 8);
      }
#pragma unroll
      for (int i = 0; i < 4; ++i)
#pragma unroll
        for (int j = 0; j < 4; ++j)
          acc[i][j] = __builtin_amdgcn_mfma_f32_16x16x32_bf16(a[i], b[j],
                                                              acc[i][j], 0, 0, 0);
    }
    __syncthreads();
  }

  // epilogue: C/D layout col = lane&15 (n), row = q*4 + r (m)  [m89/m91]
  float pv[4][4];
#pragma unroll
  for (int i = 0; i < 4; ++i)
#pragma unroll
    for (int r = 0; r < 4; ++r) pv[i][r] = p[m0 + wm + i * 16 + q * 4 + r];
#pragma unroll
  for (int j = 0; j < 4; ++j) {
    const int n = n0 + wn + j * 16 + col;
    const float bev = be[n];
#pragma unroll
    for (int i = 0; i < 4; ++i) {
#pragma unroll
      for (int r = 0; r < 4; ++r) {
        const int m = m0 + wm + i * 16 + q * 4 + r;
        out[(size_t)m * HDIM + n] = (acc[i][j][r] + bev) * pv[i][r];
      }
    }
  }
}

// ---------------------------------------------------------------------------
extern "C" void kernel_launch(void* const* d_in, const int* in_sizes, int n_in,
                              void* d_out, int out_size, void* d_ws, size_t ws_size,
                              hipStream_t stream) {
  const float* x  = (const float*)d_in[0];
  const float* Wg = (const float*)d_in[1];
  const float* bg = (const float*)d_in[2];
  const float* We = (const float*)d_in[3];
  const float* be = (const float*)d_in[4];
  float* out = (float*)d_out;

  // workspace layout (needs 69,337,088 B):
  char* ws = (char*)d_ws;
  unsigned short* xb = (unsigned short*)ws;                         // 67,108,864 B
  unsigned short* wt = (unsigned short*)(ws + (size_t)67108864);    //  2,097,152 B
  float* p = (float*)(ws + (size_t)67108864 + 2097152);             //    131,072 B

  router_convert<<<NTOK / 64, 512, 0, stream>>>(x, Wg, bg, xb, p);
  transpose_convert<<<dim3(16, 16), 256, 0, stream>>>(We, wt);
  moe_gemm<<<2048, 256, 0, stream>>>(xb, wt, be, p, out);
}

// Round 4
// 345.530 us; speedup vs baseline: 1.5290x; 1.2001x over previous
//
#include <hip/hip_runtime.h>
#include <stdint.h>

// Problem constants: B=8, S=4096, H=1024, E=8 -> N = 32768 tokens.
#define HDIM 1024
#define NEXP 8
#define NTOK 32768
#define BM 128
#define BN 128
#define BK 32

typedef __attribute__((ext_vector_type(4))) float f32x4;
typedef __attribute__((ext_vector_type(8))) short bf16x8;

// fp32 -> bf16 bits, round-to-nearest-even
__device__ __forceinline__ unsigned short f2bf(float f) {
  union { float f; unsigned u; } v; v.f = f;
  unsigned r = v.u + 0x7FFF + ((v.u >> 16) & 1);
  return (unsigned short)(r >> 16);
}

// async global->LDS, 16B per lane. LDS dest must be wave-uniform base + lane*16.
__device__ __forceinline__ void gload_lds16(const void* g, void* l) {
  __builtin_amdgcn_global_load_lds(
      (__attribute__((address_space(1))) void*)(g),
      (__attribute__((address_space(3))) void*)(l), 16, 0, 0);
}

// ---------------------------------------------------------------------------
// Kernel 1: router (fp32 exact) + x -> bf16 conversion, one pass over x.
// Round-1-proven version (LDS-tile, wave-uniform Wg s_loads). The round-3
// shfl variant regressed (~+35 us): its per-lane Wg loads were 4B-scattered
// VMEM; this one keeps Wg wave-uniform -> scalar loads.
//   - block owns 64 tokens; loop over 8 chunks of 128 floats.
//   - LOAD phase: coalesced float4 reads, bf16 convert + coalesced uint2
//     stores, fp32 staged to LDS tile [64][132] (conflict-free b128).
//   - COMPUTE phase: lane = token, wave w owns k in [w*16, w*16+16).
//   - partial logits reduced through LDS; first 64 threads finalize.
// ---------------------------------------------------------------------------
__global__ __launch_bounds__(512) void router_convert(
    const float* __restrict__ x, const float* __restrict__ Wg,
    const float* __restrict__ bg, unsigned short* __restrict__ xb,
    float* __restrict__ p) {
  __shared__ float tile[64][132];        // 33,792 B
  __shared__ float part[8][64][NEXP];    // 16,384 B
  const int t = threadIdx.x;
  const int lane = t & 63;
  const int wu = __builtin_amdgcn_readfirstlane(t >> 6);  // wave id, SGPR
  const int tok0 = blockIdx.x * 64;

  float acc[NEXP];
#pragma unroll
  for (int e = 0; e < NEXP; ++e) acc[e] = 0.f;

  for (int ck = 0; ck < 8; ++ck) {
    // ---- load + convert + LDS stage (coalesced) ----
#pragma unroll
    for (int i = 0; i < 4; ++i) {
      const int idx = i * 512 + t;       // 0..2047 over [64 rows][32 float4]
      const int r = idx >> 5, c4 = idx & 31;
      const size_t goff = (size_t)(tok0 + r) * HDIM + ck * 128 + c4 * 4;
      const float4 v = *(const float4*)(x + goff);
      union { unsigned short us[4]; uint2 u2; } pk;
      pk.us[0] = f2bf(v.x); pk.us[1] = f2bf(v.y);
      pk.us[2] = f2bf(v.z); pk.us[3] = f2bf(v.w);
      *(uint2*)(xb + goff) = pk.u2;
      *(float4*)(&tile[r][c4 * 4]) = v;  // ds_write_b128, conflict-free
    }
    __syncthreads();

    // ---- compute: lane = token, wave-uniform k-range -> scalar Wg loads ----
    const float* wr = Wg + ((size_t)ck * 128 + wu * 16) * NEXP;
#pragma unroll
    for (int q = 0; q < 4; ++q) {
      const float4 f = *(const float4*)(&tile[lane][wu * 16 + q * 4]);
      const float fv[4] = {f.x, f.y, f.z, f.w};
#pragma unroll
      for (int j = 0; j < 4; ++j)
#pragma unroll
        for (int e = 0; e < NEXP; ++e)
          acc[e] += fv[j] * wr[(q * 4 + j) * NEXP + e];
    }
    __syncthreads();
  }

#pragma unroll
  for (int e = 0; e < NEXP; ++e) part[wu][lane][e] = acc[e];
  __syncthreads();

  if (t < 64) {
    float l[NEXP];
#pragma unroll
    for (int e = 0; e < NEXP; ++e) {
      float s = bg[e];
#pragma unroll
      for (int c = 0; c < 8; ++c) s += part[c][t][e];
      l[e] = s;
    }
    float mx = l[0];
#pragma unroll
    for (int e = 1; e < NEXP; ++e) mx = fmaxf(mx, l[e]);
    float s = 0.f;
#pragma unroll
    for (int e = 0; e < NEXP; ++e) s += __expf(l[e] - mx);
    p[tok0 + t] = 1.0f / s;  // softmax prob of the argmax = exp(0)/sum
  }
}

// ---------------------------------------------------------------------------
// Kernel 2: We [k][n] fp32 -> Wt [n][k] bf16 (transpose + convert). Unchanged.
// ---------------------------------------------------------------------------
__global__ __launch_bounds__(256) void transpose_convert(
    const float* __restrict__ We, unsigned short* __restrict__ wt) {
  __shared__ float tile[64][65];
  const int bj = blockIdx.x, bi = blockIdx.y;
  const int tx = threadIdx.x & 63, ty = threadIdx.x >> 6;
#pragma unroll
  for (int i = 0; i < 16; ++i) {
    int row = i * 4 + ty;
    tile[row][tx] = We[(size_t)(bi * 64 + row) * HDIM + bj * 64 + tx];
  }
  __syncthreads();
#pragma unroll
  for (int i = 0; i < 16; ++i) {
    int row = i * 4 + ty;
    wt[(size_t)(bj * 64 + row) * HDIM + bi * 64 + tx] = f2bf(tile[tx][row]);
  }
}

// ---------------------------------------------------------------------------
// Kernel 3: C[m][n] = (A[m][:] @ We[:][n] + be[n]) * p[m], bf16 MFMA.
// R4: round-1 coalesced staging + XOR slot swizzle + T3-min double-buffer.
//  - Staging order (round-1): granule c: row=c>>2, s=c&3 -> 4 lanes share a
//    64B row segment (16 cache lines/wave; the round-3 remap's 64-row scatter
//    was the 110->152 regression).
//  - XOR swizzle (both sides): granule c holds A[row][(s^(row&3))*8..+8];
//    source address applies the XOR (stays in the same 64B segment ->
//    coalescing kept). Frag read granule = row'*4 + (q^(col&3)) ->
//    bank-quads spread evenly, 2-way max (free, m136). Fixes round-1's
//    8.4M SQ_LDS_BANK_CONFLICT without the round-3 source scatter.
//  - T3-minimum 2-phase (guide 5.5): double-buffered LDS (32 KB), prefetch
//    of tile k+1 issued BEFORE ds_read+MFMA of tile k, ONE __syncthreads
//    per K-step (vmcnt+lgkm drain) -> staging latency hides under MFMA.
// XCD-aware swizzle unchanged: block -> XCD lin&7; n-blocks inner.
// ---------------------------------------------------------------------------
__global__ __launch_bounds__(256) void moe_gemm(
    const unsigned short* __restrict__ A, const unsigned short* __restrict__ Bt,
    const float* __restrict__ be, const float* __restrict__ p,
    float* __restrict__ out) {
  __shared__ __align__(16) unsigned short As[2][BM * BK];  // 2 x 8 KB
  __shared__ __align__(16) unsigned short Bs[2][BN * BK];  // 2 x 8 KB
  const int t = threadIdx.x;

  const unsigned lin = blockIdx.x;            // 2048 blocks
  const unsigned xcd = lin & 7, idx = lin >> 3;
  const int n0 = (int)(idx & 7) * BN;          // 8 n-blocks inner
  const int m0 = (int)(xcd * 32 + (idx >> 3)) * BM;  // 32 m-panels per XCD

  // staging: granules t and t+256. row = c>>2, s = c&3; (row+64)&3 == row&3.
  const int r0 = t >> 2, s0 = t & 3;
  const int ka = (s0 ^ (r0 & 3)) * 8;  // XOR-swizzled k-offset (shorts)
  const unsigned short* ga0 = A + (size_t)(m0 + r0) * HDIM + ka;
  const unsigned short* ga1 = A + (size_t)(m0 + r0 + 64) * HDIM + ka;
  const unsigned short* gb0 = Bt + (size_t)(n0 + r0) * HDIM + ka;
  const unsigned short* gb1 = Bt + (size_t)(n0 + r0 + 64) * HDIM + ka;

  const int lane = t & 63, wid = t >> 6;
  const int wm = (wid >> 1) * 64, wn = (wid & 1) * 64;
  const int col = lane & 15, q = lane >> 4;  // frag: row=col, k=q*8+i
  const int slot = q ^ (col & 3);            // swizzled granule slot

  // frag read offsets (shorts) within a buffer
  int offA[4], offB[4];
#pragma unroll
  for (int i = 0; i < 4; ++i) {
    offA[i] = ((wm + i * 16 + col) * 4 + slot) * 8;
    offB[i] = ((wn + i * 16 + col) * 4 + slot) * 8;
  }

  f32x4 acc[4][4] = {};

  // prologue: stage tile 0 into buffer 0
  gload_lds16(ga0, &As[0][t * 8]);
  gload_lds16(ga1, &As[0][(t + 256) * 8]);
  gload_lds16(gb0, &Bs[0][t * 8]);
  gload_lds16(gb1, &Bs[0][(t + 256) * 8]);
  ga0 += BK; ga1 += BK; gb0 += BK; gb1 += BK;
  __syncthreads();

  int cur = 0;
  for (int k0 = 0; k0 < HDIM; k0 += BK) {
    if (k0 + BK < HDIM) {  // issue next-tile prefetch BEFORE compute
      const int nb = cur ^ 1;
      gload_lds16(ga0, &As[nb][t * 8]);
      gload_lds16(ga1, &As[nb][(t + 256) * 8]);
      gload_lds16(gb0, &Bs[nb][t * 8]);
      gload_lds16(gb1, &Bs[nb][(t + 256) * 8]);
      ga0 += BK; ga1 += BK; gb0 += BK; gb1 += BK;
    }
    bf16x8 a[4], b[4];
#pragma unroll
    for (int i = 0; i < 4; ++i) {
      a[i] = *(const bf16x8*)(&As[cur][offA[i]]);
      b[i] = *(const bf16x8*)(&Bs[cur][offB[i]]);
    }
#pragma unroll
    for (int i = 0; i < 4; ++i)
#pragma unroll
      for (int j = 0; j < 4; ++j)
        acc[i][j] =
            __builtin_amdgcn_mfma_f32_16x16x32_bf16(a[i], b[j], acc[i][j], 0, 0, 0);
    __syncthreads();  // drains vmcnt (prefetch landed) + all waves done reading
    cur ^= 1;
  }

  // epilogue: C/D layout col = lane&15 (n), row = q*4 + r (m)  [m89/m91]
  float pv[4][4];
#pragma unroll
  for (int i = 0; i < 4; ++i)
#pragma unroll
    for (int r = 0; r < 4; ++r) pv[i][r] = p[m0 + wm + i * 16 + q * 4 + r];
#pragma unroll
  for (int j = 0; j < 4; ++j) {
    const int n = n0 + wn + j * 16 + col;
    const float bev = be[n];
#pragma unroll
    for (int i = 0; i < 4; ++i) {
#pragma unroll
      for (int r = 0; r < 4; ++r) {
        const int m = m0 + wm + i * 16 + q * 4 + r;
        out[(size_t)m * HDIM + n] = (acc[i][j][r] + bev) * pv[i][r];
      }
    }
  }
}

// ---------------------------------------------------------------------------
extern "C" void kernel_launch(void* const* d_in, const int* in_sizes, int n_in,
                              void* d_out, int out_size, void* d_ws, size_t ws_size,
                              hipStream_t stream) {
  const float* x  = (const float*)d_in[0];
  const float* Wg = (const float*)d_in[1];
  const float* bg = (const float*)d_in[2];
  const float* We = (const float*)d_in[3];
  const float* be = (const float*)d_in[4];
  float* out = (float*)d_out;

  // workspace layout (needs 69,337,088 B):
  char* ws = (char*)d_ws;
  unsigned short* xb = (unsigned short*)ws;                         // 67,108,864 B
  unsigned short* wt = (unsigned short*)(ws + (size_t)67108864);    //  2,097,152 B
  float* p = (float*)(ws + (size_t)67108864 + 2097152);             //    131,072 B

  router_convert<<<NTOK / 64, 512, 0, stream>>>(x, Wg, bg, xb, p);
  transpose_convert<<<dim3(16, 16), 256, 0, stream>>>(We, wt);
  moe_gemm<<<2048, 256, 0, stream>>>(xb, wt, be, p, out);
}

// Round 5
// 327.715 us; speedup vs baseline: 1.6121x; 1.0544x over previous
//
#include <hip/hip_runtime.h>
#include <stdint.h>

// Problem constants: B=8, S=4096, H=1024, E=8 -> N = 32768 tokens.
#define HDIM 1024
#define NEXP 8
#define NTOK 32768
#define BM 128
#define BN 128
#define BK 64

typedef __attribute__((ext_vector_type(4))) float f32x4;
typedef __attribute__((ext_vector_type(8))) short bf16x8;

// fp32 -> bf16 bits, round-to-nearest-even
__device__ __forceinline__ unsigned short f2bf(float f) {
  union { float f; unsigned u; } v; v.f = f;
  unsigned r = v.u + 0x7FFF + ((v.u >> 16) & 1);
  return (unsigned short)(r >> 16);
}

// async global->LDS, 16B per lane. LDS dest must be wave-uniform base + lane*16.
__device__ __forceinline__ void gload_lds16(const void* g, void* l) {
  __builtin_amdgcn_global_load_lds(
      (__attribute__((address_space(1))) void*)(g),
      (__attribute__((address_space(3))) void*)(l), 16, 0, 0);
}

// ---------------------------------------------------------------------------
// Kernel 1: router (fp32 exact) + x -> bf16 conversion, one pass over x.
// Round-1-proven version (LDS-tile, wave-uniform Wg s_loads).
//   - block owns 64 tokens; loop over 8 chunks of 128 floats.
//   - LOAD phase: coalesced float4 reads, bf16 convert + coalesced uint2
//     stores, fp32 staged to LDS tile [64][132] (conflict-free b128).
//   - COMPUTE phase: lane = token, wave w owns k in [w*16, w*16+16).
//   - partial logits reduced through LDS; first 64 threads finalize.
// ---------------------------------------------------------------------------
__global__ __launch_bounds__(512) void router_convert(
    const float* __restrict__ x, const float* __restrict__ Wg,
    const float* __restrict__ bg, unsigned short* __restrict__ xb,
    float* __restrict__ p) {
  __shared__ float tile[64][132];        // 33,792 B
  __shared__ float part[8][64][NEXP];    // 16,384 B
  const int t = threadIdx.x;
  const int lane = t & 63;
  const int wu = __builtin_amdgcn_readfirstlane(t >> 6);  // wave id, SGPR
  const int tok0 = blockIdx.x * 64;

  float acc[NEXP];
#pragma unroll
  for (int e = 0; e < NEXP; ++e) acc[e] = 0.f;

  for (int ck = 0; ck < 8; ++ck) {
    // ---- load + convert + LDS stage (coalesced) ----
#pragma unroll
    for (int i = 0; i < 4; ++i) {
      const int idx = i * 512 + t;       // 0..2047 over [64 rows][32 float4]
      const int r = idx >> 5, c4 = idx & 31;
      const size_t goff = (size_t)(tok0 + r) * HDIM + ck * 128 + c4 * 4;
      const float4 v = *(const float4*)(x + goff);
      union { unsigned short us[4]; uint2 u2; } pk;
      pk.us[0] = f2bf(v.x); pk.us[1] = f2bf(v.y);
      pk.us[2] = f2bf(v.z); pk.us[3] = f2bf(v.w);
      *(uint2*)(xb + goff) = pk.u2;
      *(float4*)(&tile[r][c4 * 4]) = v;  // ds_write_b128, conflict-free
    }
    __syncthreads();

    // ---- compute: lane = token, wave-uniform k-range -> scalar Wg loads ----
    const float* wr = Wg + ((size_t)ck * 128 + wu * 16) * NEXP;
#pragma unroll
    for (int q = 0; q < 4; ++q) {
      const float4 f = *(const float4*)(&tile[lane][wu * 16 + q * 4]);
      const float fv[4] = {f.x, f.y, f.z, f.w};
#pragma unroll
      for (int j = 0; j < 4; ++j)
#pragma unroll
        for (int e = 0; e < NEXP; ++e)
          acc[e] += fv[j] * wr[(q * 4 + j) * NEXP + e];
    }
    __syncthreads();
  }

#pragma unroll
  for (int e = 0; e < NEXP; ++e) part[wu][lane][e] = acc[e];
  __syncthreads();

  if (t < 64) {
    float l[NEXP];
#pragma unroll
    for (int e = 0; e < NEXP; ++e) {
      float s = bg[e];
#pragma unroll
      for (int c = 0; c < 8; ++c) s += part[c][t][e];
      l[e] = s;
    }
    float mx = l[0];
#pragma unroll
    for (int e = 1; e < NEXP; ++e) mx = fmaxf(mx, l[e]);
    float s = 0.f;
#pragma unroll
    for (int e = 0; e < NEXP; ++e) s += __expf(l[e] - mx);
    p[tok0 + t] = 1.0f / s;  // softmax prob of the argmax = exp(0)/sum
  }
}

// ---------------------------------------------------------------------------
// Kernel 2: We [k][n] fp32 -> Wt [n][k] bf16 (transpose + convert). Unchanged.
// ---------------------------------------------------------------------------
__global__ __launch_bounds__(256) void transpose_convert(
    const float* __restrict__ We, unsigned short* __restrict__ wt) {
  __shared__ float tile[64][65];
  const int bj = blockIdx.x, bi = blockIdx.y;
  const int tx = threadIdx.x & 63, ty = threadIdx.x >> 6;
#pragma unroll
  for (int i = 0; i < 16; ++i) {
    int row = i * 4 + ty;
    tile[row][tx] = We[(size_t)(bi * 64 + row) * HDIM + bj * 64 + tx];
  }
  __syncthreads();
#pragma unroll
  for (int i = 0; i < 16; ++i) {
    int row = i * 4 + ty;
    wt[(size_t)(bj * 64 + row) * HDIM + bi * 64 + tx] = f2bf(tile[tx][row]);
  }
}

// ---------------------------------------------------------------------------
// Kernel 3: C[m][n] = (A[m][:] @ We[:][n] + be[n]) * p[m], bf16 MFMA.
// R5: BK=64 + rank-3 XOR swizzle satisfying BOTH sides (rule #21):
//  - LDS granule g = row*8 + s (16B granules; row stride = 8 granules =
//    128 B) holds A[row][k0 + (s ^ (row&7))*8 .. +8].
//  - Staging (coalesced like round 1): thread t, chunk c = t+256*i:
//    row = c>>3, s = c&7 -> 8 consecutive lanes share one 128 B row-chunk;
//    the XOR permutes 16B granules WITHIN the chunk -> same cache lines
//    (round-3's row=c&127 scatter was the 110->152 regression).
//  - Frag read k-granule q' = kk*4+q lands on slot q' ^ (col&7): any 8
//    consecutive lanes hit 8 DISTINCT slots (row&7 == col&7 since wm and
//    i*16 are multiples of 16). Round-4's swizzle had rank 2 (4*col
//    collapses mod 8) -> 4 slots -> the unchanged 8.4M conflicts.
//  - BK=64 halves barrier count vs round 1 (16 K-iters, 32 MFMA per
//    compute phase). Single buffer, 32 KB LDS (dbuf measured neutral in
//    round 4; 64 KB LDS risks the m132 occupancy cliff).
// XCD-aware swizzle unchanged: block -> XCD lin&7; n-blocks inner.
// ---------------------------------------------------------------------------
__global__ __launch_bounds__(256) void moe_gemm(
    const unsigned short* __restrict__ A, const unsigned short* __restrict__ Bt,
    const float* __restrict__ be, const float* __restrict__ p,
    float* __restrict__ out) {
  __shared__ __align__(16) unsigned short As[BM * BK];  // 16 KB
  __shared__ __align__(16) unsigned short Bs[BN * BK];  // 16 KB
  const int t = threadIdx.x;

  const unsigned lin = blockIdx.x;            // 2048 blocks
  const unsigned xcd = lin & 7, idx = lin >> 3;
  const int n0 = (int)(idx & 7) * BN;          // 8 n-blocks inner
  const int m0 = (int)(xcd * 32 + (idx >> 3)) * BM;  // 32 m-panels per XCD

  // staging: 1024 granules per matrix; thread t takes chunks t + 256*i.
  const unsigned short* ga[4];
  const unsigned short* gb[4];
  unsigned short* la[4];
  unsigned short* lb[4];
#pragma unroll
  for (int i = 0; i < 4; ++i) {
    const int c = t + 256 * i;
    const int row = c >> 3, s = c & 7;
    const int ka = (s ^ (row & 7)) * 8;  // XOR-swizzled 16B granule in row
    ga[i] = A + (size_t)(m0 + row) * HDIM + ka;
    gb[i] = Bt + (size_t)(n0 + row) * HDIM + ka;
    la[i] = As + (size_t)c * 8;
    lb[i] = Bs + (size_t)c * 8;
  }

  const int lane = t & 63, wid = t >> 6;
  const int wm = (wid >> 1) * 64, wn = (wid & 1) * 64;
  const int col = lane & 15, q = lane >> 4;  // frag: row=col, k=q*8+i

  // frag read offsets (shorts): granule = row*8 + ((kk*4+q) ^ (col&7))
  int offA[2][4], offB[2][4];
#pragma unroll
  for (int kk = 0; kk < 2; ++kk)
#pragma unroll
    for (int i = 0; i < 4; ++i) {
      const int sl = (kk * 4 + q) ^ (col & 7);
      offA[kk][i] = ((wm + i * 16 + col) * 8 + sl) * 8;
      offB[kk][i] = ((wn + i * 16 + col) * 8 + sl) * 8;
    }

  f32x4 acc[4][4] = {};

  for (int k0 = 0; k0 < HDIM; k0 += BK) {
#pragma unroll
    for (int i = 0; i < 4; ++i) gload_lds16(ga[i], la[i]);
#pragma unroll
    for (int i = 0; i < 4; ++i) gload_lds16(gb[i], lb[i]);
#pragma unroll
    for (int i = 0; i < 4; ++i) { ga[i] += BK; gb[i] += BK; }
    __syncthreads();
#pragma unroll
    for (int kk = 0; kk < 2; ++kk) {
      bf16x8 a[4], b[4];
#pragma unroll
      for (int i = 0; i < 4; ++i) {
        a[i] = *(const bf16x8*)(As + offA[kk][i]);
        b[i] = *(const bf16x8*)(Bs + offB[kk][i]);
      }
#pragma unroll
      for (int i = 0; i < 4; ++i)
#pragma unroll
        for (int j = 0; j < 4; ++j)
          acc[i][j] = __builtin_amdgcn_mfma_f32_16x16x32_bf16(a[i], b[j],
                                                              acc[i][j], 0, 0, 0);
    }
    __syncthreads();
  }

  // epilogue: C/D layout col = lane&15 (n), row = q*4 + r (m)  [m89/m91]
  float pv[4][4];
#pragma unroll
  for (int i = 0; i < 4; ++i)
#pragma unroll
    for (int r = 0; r < 4; ++r) pv[i][r] = p[m0 + wm + i * 16 + q * 4 + r];
#pragma unroll
  for (int j = 0; j < 4; ++j) {
    const int n = n0 + wn + j * 16 + col;
    const float bev = be[n];
#pragma unroll
    for (int i = 0; i < 4; ++i) {
#pragma unroll
      for (int r = 0; r < 4; ++r) {
        const int m = m0 + wm + i * 16 + q * 4 + r;
        out[(size_t)m * HDIM + n] = (acc[i][j][r] + bev) * pv[i][r];
      }
    }
  }
}

// ---------------------------------------------------------------------------
extern "C" void kernel_launch(void* const* d_in, const int* in_sizes, int n_in,
                              void* d_out, int out_size, void* d_ws, size_t ws_size,
                              hipStream_t stream) {
  const float* x  = (const float*)d_in[0];
  const float* Wg = (const float*)d_in[1];
  const float* bg = (const float*)d_in[2];
  const float* We = (const float*)d_in[3];
  const float* be = (const float*)d_in[4];
  float* out = (float*)d_out;

  // workspace layout (needs 69,337,088 B):
  char* ws = (char*)d_ws;
  unsigned short* xb = (unsigned short*)ws;                         // 67,108,864 B
  unsigned short* wt = (unsigned short*)(ws + (size_t)67108864);    //  2,097,152 B
  float* p = (float*)(ws + (size_t)67108864 + 2097152);             //    131,072 B

  router_convert<<<NTOK / 64, 512, 0, stream>>>(x, Wg, bg, xb, p);
  transpose_convert<<<dim3(16, 16), 256, 0, stream>>>(We, wt);
  moe_gemm<<<2048, 256, 0, stream>>>(xb, wt, be, p, out);
}

// Round 6
// 325.379 us; speedup vs baseline: 1.6237x; 1.0072x over previous
//
#include <hip/hip_runtime.h>
#include <stdint.h>

// Problem constants: B=8, S=4096, H=1024, E=8 -> N = 32768 tokens.
#define HDIM 1024
#define NEXP 8
#define NTOK 32768
#define BM 128
#define BN 128
#define BK 64

typedef __attribute__((ext_vector_type(4))) float f32x4;
typedef __attribute__((ext_vector_type(8))) short bf16x8;

// fp32 -> bf16 bits, round-to-nearest-even
__device__ __forceinline__ unsigned short f2bf(float f) {
  union { float f; unsigned u; } v; v.f = f;
  unsigned r = v.u + 0x7FFF + ((v.u >> 16) & 1);
  return (unsigned short)(r >> 16);
}

// async global->LDS, 16B per lane. LDS dest must be wave-uniform base + lane*16.
__device__ __forceinline__ void gload_lds16(const void* g, void* l) {
  __builtin_amdgcn_global_load_lds(
      (__attribute__((address_space(1))) void*)(g),
      (__attribute__((address_space(3))) void*)(l), 16, 0, 0);
}

// ---------------------------------------------------------------------------
// Kernel 1: router (fp32 exact) + x -> bf16 conversion, one pass over x.
// R6: round-1 structure + T14 async split: chunk ck+1's global loads are
// issued BEFORE chunk ck's compute phase -> HBM latency hides under the
// 128-FMA compute + barrier instead of serializing with it. xb stores
// also overlap compute. Math unchanged (fp32, same summation order).
// ---------------------------------------------------------------------------
__global__ __launch_bounds__(512) void router_convert(
    const float* __restrict__ x, const float* __restrict__ Wg,
    const float* __restrict__ bg, unsigned short* __restrict__ xb,
    float* __restrict__ p) {
  __shared__ float tile[64][132];        // 33,792 B
  __shared__ float part[8][64][NEXP];    // 16,384 B
  const int t = threadIdx.x;
  const int lane = t & 63;
  const int wu = __builtin_amdgcn_readfirstlane(t >> 6);  // wave id, SGPR
  const int tok0 = blockIdx.x * 64;

  float acc[NEXP];
#pragma unroll
  for (int e = 0; e < NEXP; ++e) acc[e] = 0.f;

  // prologue: load chunk 0 into registers
  float4 v[4], vn[4];
#pragma unroll
  for (int i = 0; i < 4; ++i) {
    const int idx = i * 512 + t;
    const int r = idx >> 5, c4 = idx & 31;
    v[i] = *(const float4*)(x + (size_t)(tok0 + r) * HDIM + c4 * 4);
  }

  for (int ck = 0; ck < 8; ++ck) {
    // ---- issue next chunk's loads (fly during this chunk's compute) ----
    if (ck < 7) {
#pragma unroll
      for (int i = 0; i < 4; ++i) {
        const int idx = i * 512 + t;
        const int r = idx >> 5, c4 = idx & 31;
        vn[i] = *(const float4*)(x + (size_t)(tok0 + r) * HDIM +
                                 (ck + 1) * 128 + c4 * 4);
      }
    }
    // ---- write phase: bf16 store + LDS tile (coalesced) ----
#pragma unroll
    for (int i = 0; i < 4; ++i) {
      const int idx = i * 512 + t;
      const int r = idx >> 5, c4 = idx & 31;
      const size_t goff = (size_t)(tok0 + r) * HDIM + ck * 128 + c4 * 4;
      union { unsigned short us[4]; uint2 u2; } pk;
      pk.us[0] = f2bf(v[i].x); pk.us[1] = f2bf(v[i].y);
      pk.us[2] = f2bf(v[i].z); pk.us[3] = f2bf(v[i].w);
      *(uint2*)(xb + goff) = pk.u2;
      *(float4*)(&tile[r][c4 * 4]) = v[i];  // ds_write_b128, conflict-free
    }
    __syncthreads();

    // ---- compute: lane = token, wave-uniform k-range -> scalar Wg loads ----
    const float* wr = Wg + ((size_t)ck * 128 + wu * 16) * NEXP;
#pragma unroll
    for (int q = 0; q < 4; ++q) {
      const float4 f = *(const float4*)(&tile[lane][wu * 16 + q * 4]);
      const float fv[4] = {f.x, f.y, f.z, f.w};
#pragma unroll
      for (int j = 0; j < 4; ++j)
#pragma unroll
        for (int e = 0; e < NEXP; ++e)
          acc[e] += fv[j] * wr[(q * 4 + j) * NEXP + e];
    }
    __syncthreads();
#pragma unroll
    for (int i = 0; i < 4; ++i) v[i] = vn[i];  // vmcnt wait lands here
  }

#pragma unroll
  for (int e = 0; e < NEXP; ++e) part[wu][lane][e] = acc[e];
  __syncthreads();

  if (t < 64) {
    float l[NEXP];
#pragma unroll
    for (int e = 0; e < NEXP; ++e) {
      float s = bg[e];
#pragma unroll
      for (int c = 0; c < 8; ++c) s += part[c][t][e];
      l[e] = s;
    }
    float mx = l[0];
#pragma unroll
    for (int e = 1; e < NEXP; ++e) mx = fmaxf(mx, l[e]);
    float s = 0.f;
#pragma unroll
    for (int e = 0; e < NEXP; ++e) s += __expf(l[e] - mx);
    p[tok0 + t] = 1.0f / s;  // softmax prob of the argmax = exp(0)/sum
  }
}

// ---------------------------------------------------------------------------
// Kernel 2: We [k][n] fp32 -> Wt [n][k] bf16 (transpose + convert). Unchanged.
// ---------------------------------------------------------------------------
__global__ __launch_bounds__(256) void transpose_convert(
    const float* __restrict__ We, unsigned short* __restrict__ wt) {
  __shared__ float tile[64][65];
  const int bj = blockIdx.x, bi = blockIdx.y;
  const int tx = threadIdx.x & 63, ty = threadIdx.x >> 6;
#pragma unroll
  for (int i = 0; i < 16; ++i) {
    int row = i * 4 + ty;
    tile[row][tx] = We[(size_t)(bi * 64 + row) * HDIM + bj * 64 + tx];
  }
  __syncthreads();
#pragma unroll
  for (int i = 0; i < 16; ++i) {
    int row = i * 4 + ty;
    wt[(size_t)(bj * 64 + row) * HDIM + bi * 64 + tx] = f2bf(tile[tx][row]);
  }
}

// ---------------------------------------------------------------------------
// Kernel 3: C[m][n] = (A[m][:] @ We[:][n] + be[n]) * p[m], bf16 MFMA.
// R6: R5 (BK=64 + rank-3 XOR swizzle, conflicts measured 0) + T4 depth-2
// pipeline with COUNTED vmcnt (never drain to 0 in the main loop):
//   prologue: stage T0->buf0, T1->buf1 (16 loads in flight)
//   iter i:   s_waitcnt vmcnt(8)   -> tile i landed; tile i+1 stays in
//             flight ACROSS the barrier (the 2-phase stall was the
//             __syncthreads vmcnt(0) drain, m233)
//             s_barrier; 32 MFMA on buf[i&1]; s_barrier;
//             issue tile i+2 -> buf[i&1]   (8 gload_lds)
// Race safety: MFMA consumes all ds_read results before barrier-2 (lgkm
// waits are compiler-inserted before MFMA), so buf[i&1] is fully read by
// every wave before any wave's T_{i+2} loads can overwrite it. Each wave
// issues exactly 8 gload_lds per tile -> all-waves vmcnt(8) + barrier
// guarantees the whole tile is staged.
// LDS 64 KB (2 blocks/CU): trading TLP for pipeline depth.
// ---------------------------------------------------------------------------
__global__ __launch_bounds__(256) void moe_gemm(
    const unsigned short* __restrict__ A, const unsigned short* __restrict__ Bt,
    const float* __restrict__ be, const float* __restrict__ p,
    float* __restrict__ out) {
  __shared__ __align__(16) unsigned short As[2][BM * BK];  // 2 x 16 KB
  __shared__ __align__(16) unsigned short Bs[2][BN * BK];  // 2 x 16 KB
  const int t = threadIdx.x;

  const unsigned lin = blockIdx.x;            // 2048 blocks
  const unsigned xcd = lin & 7, idx = lin >> 3;
  const int n0 = (int)(idx & 7) * BN;          // 8 n-blocks inner
  const int m0 = (int)(xcd * 32 + (idx >> 3)) * BM;  // 32 m-panels per XCD

  // staging: granule c = t + 256*i: row = c>>3, s = c&7; source applies the
  // XOR within the 128 B row-chunk -> coalescing preserved (16 lines/wave).
  const unsigned short* ga[4];
  const unsigned short* gb[4];
#pragma unroll
  for (int i = 0; i < 4; ++i) {
    const int c = t + 256 * i;
    const int row = c >> 3, s = c & 7;
    const int ka = (s ^ (row & 7)) * 8;  // XOR-swizzled 16B granule in row
    ga[i] = A + (size_t)(m0 + row) * HDIM + ka;
    gb[i] = Bt + (size_t)(n0 + row) * HDIM + ka;
  }

  const int lane = t & 63, wid = t >> 6;
  const int wm = (wid >> 1) * 64, wn = (wid & 1) * 64;
  const int col = lane & 15, q = lane >> 4;  // frag: row=col, k=q*8+i

  // frag read offsets (shorts): granule = row*8 + ((kk*4+q) ^ (col&7))
  // -> any 8 consecutive lanes hit 8 distinct 16B slots (rank-3, R5: 0 confl)
  int offA[2][4], offB[2][4];
#pragma unroll
  for (int kk = 0; kk < 2; ++kk)
#pragma unroll
    for (int i = 0; i < 4; ++i) {
      const int sl = (kk * 4 + q) ^ (col & 7);
      offA[kk][i] = ((wm + i * 16 + col) * 8 + sl) * 8;
      offB[kk][i] = ((wn + i * 16 + col) * 8 + sl) * 8;
    }

  f32x4 acc[4][4] = {};

  // ---- stage helper: 8 gload_lds for one tile into buffer b, advance ----
  auto stage = [&](int b) {
#pragma unroll
    for (int i = 0; i < 4; ++i) gload_lds16(ga[i], &As[b][(t + 256 * i) * 8]);
#pragma unroll
    for (int i = 0; i < 4; ++i) gload_lds16(gb[i], &Bs[b][(t + 256 * i) * 8]);
#pragma unroll
    for (int i = 0; i < 4; ++i) { ga[i] += BK; gb[i] += BK; }
  };

  // prologue: two tiles in flight
  stage(0);
  stage(1);

  int cur = 0;
  for (int it = 0; it < HDIM / BK; ++it) {  // 16 iterations
    if (it < HDIM / BK - 1)
      asm volatile("s_waitcnt vmcnt(8)" ::: "memory");  // tile it landed
    else
      asm volatile("s_waitcnt vmcnt(0)" ::: "memory");  // final drain
    __builtin_amdgcn_s_barrier();

#pragma unroll
    for (int kk = 0; kk < 2; ++kk) {
      bf16x8 a[4], b[4];
#pragma unroll
      for (int i = 0; i < 4; ++i) {
        a[i] = *(const bf16x8*)(&As[cur][offA[kk][i]]);
        b[i] = *(const bf16x8*)(&Bs[cur][offB[kk][i]]);
      }
#pragma unroll
      for (int i = 0; i < 4; ++i)
#pragma unroll
        for (int j = 0; j < 4; ++j)
          acc[i][j] = __builtin_amdgcn_mfma_f32_16x16x32_bf16(a[i], b[j],
                                                              acc[i][j], 0, 0, 0);
    }
    __builtin_amdgcn_s_barrier();  // all waves done reading buf[cur]

    if (it < HDIM / BK - 2) stage(cur);  // tile it+2 -> buf[cur]
    cur ^= 1;
  }

  // epilogue: C/D layout col = lane&15 (n), row = q*4 + r (m)  [m89/m91]
  float pv[4][4];
#pragma unroll
  for (int i = 0; i < 4; ++i)
#pragma unroll
    for (int r = 0; r < 4; ++r) pv[i][r] = p[m0 + wm + i * 16 + q * 4 + r];
#pragma unroll
  for (int j = 0; j < 4; ++j) {
    const int n = n0 + wn + j * 16 + col;
    const float bev = be[n];
#pragma unroll
    for (int i = 0; i < 4; ++i) {
#pragma unroll
      for (int r = 0; r < 4; ++r) {
        const int m = m0 + wm + i * 16 + q * 4 + r;
        out[(size_t)m * HDIM + n] = (acc[i][j][r] + bev) * pv[i][r];
      }
    }
  }
}

// ---------------------------------------------------------------------------
extern "C" void kernel_launch(void* const* d_in, const int* in_sizes, int n_in,
                              void* d_out, int out_size, void* d_ws, size_t ws_size,
                              hipStream_t stream) {
  const float* x  = (const float*)d_in[0];
  const float* Wg = (const float*)d_in[1];
  const float* bg = (const float*)d_in[2];
  const float* We = (const float*)d_in[3];
  const float* be = (const float*)d_in[4];
  float* out = (float*)d_out;

  // workspace layout (needs 69,337,088 B):
  char* ws = (char*)d_ws;
  unsigned short* xb = (unsigned short*)ws;                         // 67,108,864 B
  unsigned short* wt = (unsigned short*)(ws + (size_t)67108864);    //  2,097,152 B
  float* p = (float*)(ws + (size_t)67108864 + 2097152);             //    131,072 B

  router_convert<<<NTOK / 64, 512, 0, stream>>>(x, Wg, bg, xb, p);
  transpose_convert<<<dim3(16, 16), 256, 0, stream>>>(We, wt);
  moe_gemm<<<2048, 256, 0, stream>>>(xb, wt, be, p, out);
}

// Round 7
// 324.273 us; speedup vs baseline: 1.6293x; 1.0034x over previous
//
#include <hip/hip_runtime.h>
#include <stdint.h>

// Problem constants: B=8, S=4096, H=1024, E=8 -> N = 32768 tokens.
#define HDIM 1024
#define NEXP 8
#define NTOK 32768
#define BM 256
#define BN 128
#define BK 64
#define NSLOT 3

typedef __attribute__((ext_vector_type(4))) float f32x4;
typedef __attribute__((ext_vector_type(8))) short bf16x8;

// fp32 -> bf16 bits, round-to-nearest-even
__device__ __forceinline__ unsigned short f2bf(float f) {
  union { float f; unsigned u; } v; v.f = f;
  unsigned r = v.u + 0x7FFF + ((v.u >> 16) & 1);
  return (unsigned short)(r >> 16);
}

// async global->LDS, 16B per lane. LDS dest must be wave-uniform base + lane*16.
__device__ __forceinline__ void gload_lds16(const void* g, void* l) {
  __builtin_amdgcn_global_load_lds(
      (__attribute__((address_space(1))) void*)(g),
      (__attribute__((address_space(3))) void*)(l), 16, 0, 0);
}

// ---------------------------------------------------------------------------
// Kernel 1: router (fp32 exact) + x -> bf16 conversion. R6 version (LDS tile,
// wave-uniform Wg s_loads, next-chunk register prefetch). Unchanged.
// ---------------------------------------------------------------------------
__global__ __launch_bounds__(512) void router_convert(
    const float* __restrict__ x, const float* __restrict__ Wg,
    const float* __restrict__ bg, unsigned short* __restrict__ xb,
    float* __restrict__ p) {
  __shared__ float tile[64][132];        // 33,792 B
  __shared__ float part[8][64][NEXP];    // 16,384 B
  const int t = threadIdx.x;
  const int lane = t & 63;
  const int wu = __builtin_amdgcn_readfirstlane(t >> 6);  // wave id, SGPR
  const int tok0 = blockIdx.x * 64;

  float acc[NEXP];
#pragma unroll
  for (int e = 0; e < NEXP; ++e) acc[e] = 0.f;

  float4 v[4], vn[4];
#pragma unroll
  for (int i = 0; i < 4; ++i) {
    const int idx = i * 512 + t;
    const int r = idx >> 5, c4 = idx & 31;
    v[i] = *(const float4*)(x + (size_t)(tok0 + r) * HDIM + c4 * 4);
  }

  for (int ck = 0; ck < 8; ++ck) {
    if (ck < 7) {
#pragma unroll
      for (int i = 0; i < 4; ++i) {
        const int idx = i * 512 + t;
        const int r = idx >> 5, c4 = idx & 31;
        vn[i] = *(const float4*)(x + (size_t)(tok0 + r) * HDIM +
                                 (ck + 1) * 128 + c4 * 4);
      }
    }
#pragma unroll
    for (int i = 0; i < 4; ++i) {
      const int idx = i * 512 + t;
      const int r = idx >> 5, c4 = idx & 31;
      const size_t goff = (size_t)(tok0 + r) * HDIM + ck * 128 + c4 * 4;
      union { unsigned short us[4]; uint2 u2; } pk;
      pk.us[0] = f2bf(v[i].x); pk.us[1] = f2bf(v[i].y);
      pk.us[2] = f2bf(v[i].z); pk.us[3] = f2bf(v[i].w);
      *(uint2*)(xb + goff) = pk.u2;
      *(float4*)(&tile[r][c4 * 4]) = v[i];
    }
    __syncthreads();

    const float* wr = Wg + ((size_t)ck * 128 + wu * 16) * NEXP;
#pragma unroll
    for (int q = 0; q < 4; ++q) {
      const float4 f = *(const float4*)(&tile[lane][wu * 16 + q * 4]);
      const float fv[4] = {f.x, f.y, f.z, f.w};
#pragma unroll
      for (int j = 0; j < 4; ++j)
#pragma unroll
        for (int e = 0; e < NEXP; ++e)
          acc[e] += fv[j] * wr[(q * 4 + j) * NEXP + e];
    }
    __syncthreads();
#pragma unroll
    for (int i = 0; i < 4; ++i) v[i] = vn[i];
  }

#pragma unroll
  for (int e = 0; e < NEXP; ++e) part[wu][lane][e] = acc[e];
  __syncthreads();

  if (t < 64) {
    float l[NEXP];
#pragma unroll
    for (int e = 0; e < NEXP; ++e) {
      float s = bg[e];
#pragma unroll
      for (int c = 0; c < 8; ++c) s += part[c][t][e];
      l[e] = s;
    }
    float mx = l[0];
#pragma unroll
    for (int e = 1; e < NEXP; ++e) mx = fmaxf(mx, l[e]);
    float s = 0.f;
#pragma unroll
    for (int e = 0; e < NEXP; ++e) s += __expf(l[e] - mx);
    p[tok0 + t] = 1.0f / s;  // softmax prob of the argmax = exp(0)/sum
  }
}

// ---------------------------------------------------------------------------
// Kernel 2: We [k][n] fp32 -> Wt [n][k] bf16 (transpose + convert). Unchanged.
// ---------------------------------------------------------------------------
__global__ __launch_bounds__(256) void transpose_convert(
    const float* __restrict__ We, unsigned short* __restrict__ wt) {
  __shared__ float tile[64][65];
  const int bj = blockIdx.x, bi = blockIdx.y;
  const int tx = threadIdx.x & 63, ty = threadIdx.x >> 6;
#pragma unroll
  for (int i = 0; i < 16; ++i) {
    int row = i * 4 + ty;
    tile[row][tx] = We[(size_t)(bi * 64 + row) * HDIM + bj * 64 + tx];
  }
  __syncthreads();
#pragma unroll
  for (int i = 0; i < 16; ++i) {
    int row = i * 4 + ty;
    wt[(size_t)(bj * 64 + row) * HDIM + bi * 64 + tx] = f2bf(tile[tx][row]);
  }
}

// ---------------------------------------------------------------------------
// Kernel 3: C[m][n] = (A[m][:] @ We[:][n] + be[n]) * p[m], bf16 MFMA.
// R7: phase-interleaved deep pipeline (T3+T4+T5), 256x128 tile, 8 waves.
//  - 3-slot LDS rotation (144 KB): tile t reads slot t%3; tile t+2 stages
//    into slot (t+2)%3 == slot of tile t-1, whose readers all passed the
//    entry barrier of tile t -> no WAR hazard, so NO vmcnt(0) in the loop.
//  - 6 gload_lds per thread per tile -> boundary wait = vmcnt(6): tile t+1
//    fully landed, tile t+2's 6 loads stay in flight ACROSS the barrier.
//    Loads have ~2 K-tiles of compute (~1300 cyc) to cover HBM latency.
//  - per K-tile, 2 phases: {8x ds_read_b128 -> issue 3 gload_lds ->
//    setprio(1) 16 MFMA setprio(0)} with a raw s_barrier between phases
//    (wave lockstep -> role-split, T5's prerequisite per m218b).
//  - rank-3 XOR swizzle from R5 (measured 0 bank conflicts) unchanged:
//    granule slot = s ^ (row&7); frag read slot = (kk*4+q) ^ (col&7).
//  - per-wave output 64x64 (4x4 frags) = same regs/epilogue as R5 (~140 VGPR).
// Grid 1024 = 8 XCD x 16 m-panels x 8 n-blocks; n-inner sweep for A-panel L2
// reuse; B (2 MB) L2-resident.
// ---------------------------------------------------------------------------
__global__ __launch_bounds__(512) void moe_gemm(
    const unsigned short* __restrict__ A, const unsigned short* __restrict__ Bt,
    const float* __restrict__ be, const float* __restrict__ p,
    float* __restrict__ out) {
  __shared__ __align__(16) unsigned short As[NSLOT][BM * BK];  // 3 x 32 KB
  __shared__ __align__(16) unsigned short Bs[NSLOT][BN * BK];  // 3 x 16 KB
  const int t = threadIdx.x;

  const unsigned lin = blockIdx.x;            // 1024 blocks
  const unsigned xcd = lin & 7, idx = lin >> 3;
  const int n0 = (int)(idx & 7) * BN;          // 8 n-blocks inner
  const int m0 = (int)(xcd * 16 + (idx >> 3)) * BM;  // 16 m-panels per XCD

  // staging: A has 2048 granules (4/thread), B has 1024 (2/thread).
  // chunk c: row = c>>3, s = c&7; source XOR keeps the 128B row-chunk ->
  // coalescing preserved; LDS dest linear (m104).
  const unsigned short* ga[4];
  const unsigned short* gb[2];
#pragma unroll
  for (int i = 0; i < 4; ++i) {
    const int c = t + 512 * i;
    const int row = c >> 3, s = c & 7;
    ga[i] = A + (size_t)(m0 + row) * HDIM + (s ^ (row & 7)) * 8;
  }
#pragma unroll
  for (int i = 0; i < 2; ++i) {
    const int c = t + 512 * i;
    const int row = c >> 3, s = c & 7;
    gb[i] = Bt + (size_t)(n0 + row) * HDIM + (s ^ (row & 7)) * 8;
  }

  const int lane = t & 63, wid = t >> 6;
  const int wm = (wid >> 1) * 64, wn = (wid & 1) * 64;  // 4M x 2N wave grid
  const int col = lane & 15, q = lane >> 4;  // frag: row=col, k=q*8+i

  // frag read offsets (shorts) within a slot: granule = row*8 + slot_xor
  int offA[2][4], offB[2][4];
#pragma unroll
  for (int kk = 0; kk < 2; ++kk)
#pragma unroll
    for (int i = 0; i < 4; ++i) {
      const int sl = (kk * 4 + q) ^ (col & 7);
      offA[kk][i] = ((wm + i * 16 + col) * 8 + sl) * 8;
      offB[kk][i] = ((wn + i * 16 + col) * 8 + sl) * 8;
    }

  f32x4 acc[4][4] = {};

  // stage halves: 3 gload_lds each (A half + B half)
  auto stage_h0 = [&](int sl) {
    gload_lds16(ga[0], &As[sl][(size_t)t * 8]);
    gload_lds16(ga[1], &As[sl][(size_t)(t + 512) * 8]);
    gload_lds16(gb[0], &Bs[sl][(size_t)t * 8]);
  };
  auto stage_h1 = [&](int sl) {
    gload_lds16(ga[2], &As[sl][(size_t)(t + 1024) * 8]);
    gload_lds16(ga[3], &As[sl][(size_t)(t + 1536) * 8]);
    gload_lds16(gb[1], &Bs[sl][(size_t)(t + 512) * 8]);
  };
  auto advance = [&] {
#pragma unroll
    for (int i = 0; i < 4; ++i) ga[i] += BK;
#pragma unroll
    for (int i = 0; i < 2; ++i) gb[i] += BK;
  };

  // prologue: tiles 0 and 1 in flight (12 loads/thread)
  stage_h0(0); stage_h1(0); advance();
  stage_h0(1); stage_h1(1); advance();

  int slot = 0;
  const int NT = HDIM / BK;  // 16
  for (int it = 0; it < NT; ++it) {
    if (it < NT - 1)
      asm volatile("s_waitcnt vmcnt(6)" ::: "memory");  // tile it landed
    else
      asm volatile("s_waitcnt vmcnt(0)" ::: "memory");  // final tile drain
    __builtin_amdgcn_s_barrier();
    const int s2 = (slot + 2 >= NSLOT) ? slot + 2 - NSLOT : slot + 2;

    // ---- phase 0: kstep 0 ----
    {
      bf16x8 a[4], b[4];
#pragma unroll
      for (int i = 0; i < 4; ++i) {
        a[i] = *(const bf16x8*)(&As[slot][offA[0][i]]);
        b[i] = *(const bf16x8*)(&Bs[slot][offB[0][i]]);
      }
      if (it < NT - 2) stage_h0(s2);  // overlaps the lgkm wait below
      __builtin_amdgcn_s_setprio(1);
#pragma unroll
      for (int i = 0; i < 4; ++i)
#pragma unroll
        for (int j = 0; j < 4; ++j)
          acc[i][j] = __builtin_amdgcn_mfma_f32_16x16x32_bf16(a[i], b[j],
                                                              acc[i][j], 0, 0, 0);
      __builtin_amdgcn_s_setprio(0);
    }
    asm volatile("" ::: "memory");
    __builtin_amdgcn_s_barrier();  // lockstep between phases (no WAR hazard)

    // ---- phase 1: kstep 1 ----
    {
      bf16x8 a[4], b[4];
#pragma unroll
      for (int i = 0; i < 4; ++i) {
        a[i] = *(const bf16x8*)(&As[slot][offA[1][i]]);
        b[i] = *(const bf16x8*)(&Bs[slot][offB[1][i]]);
      }
      if (it < NT - 2) { stage_h1(s2); advance(); }
      __builtin_amdgcn_s_setprio(1);
#pragma unroll
      for (int i = 0; i < 4; ++i)
#pragma unroll
        for (int j = 0; j < 4; ++j)
          acc[i][j] = __builtin_amdgcn_mfma_f32_16x16x32_bf16(a[i], b[j],
                                                              acc[i][j], 0, 0, 0);
      __builtin_amdgcn_s_setprio(0);
    }
    slot = (slot + 1 >= NSLOT) ? 0 : slot + 1;
  }

  // epilogue: C/D layout col = lane&15 (n), row = q*4 + r (m)  [m89/m91]
  float pv[4][4];
#pragma unroll
  for (int i = 0; i < 4; ++i)
#pragma unroll
    for (int r = 0; r < 4; ++r) pv[i][r] = p[m0 + wm + i * 16 + q * 4 + r];
#pragma unroll
  for (int j = 0; j < 4; ++j) {
    const int n = n0 + wn + j * 16 + col;
    const float bev = be[n];
#pragma unroll
    for (int i = 0; i < 4; ++i) {
#pragma unroll
      for (int r = 0; r < 4; ++r) {
        const int m = m0 + wm + i * 16 + q * 4 + r;
        out[(size_t)m * HDIM + n] = (acc[i][j][r] + bev) * pv[i][r];
      }
    }
  }
}

// ---------------------------------------------------------------------------
extern "C" void kernel_launch(void* const* d_in, const int* in_sizes, int n_in,
                              void* d_out, int out_size, void* d_ws, size_t ws_size,
                              hipStream_t stream) {
  const float* x  = (const float*)d_in[0];
  const float* Wg = (const float*)d_in[1];
  const float* bg = (const float*)d_in[2];
  const float* We = (const float*)d_in[3];
  const float* be = (const float*)d_in[4];
  float* out = (float*)d_out;

  // workspace layout (needs 69,337,088 B):
  char* ws = (char*)d_ws;
  unsigned short* xb = (unsigned short*)ws;                         // 67,108,864 B
  unsigned short* wt = (unsigned short*)(ws + (size_t)67108864);    //  2,097,152 B
  float* p = (float*)(ws + (size_t)67108864 + 2097152);             //    131,072 B

  router_convert<<<NTOK / 64, 512, 0, stream>>>(x, Wg, bg, xb, p);
  transpose_convert<<<dim3(16, 16), 256, 0, stream>>>(We, wt);
  moe_gemm<<<NTOK / BM * (HDIM / BN), 512, 0, stream>>>(xb, wt, be, p, out);
}